// Round 6
// baseline (151.735 us; speedup 1.0000x reference)
//
#include <hip/hip_runtime.h>
#include <stdint.h>

#define NNODES 1024
#define NGRAPH 128
#define TOPK   16384
#define EQCAP  4096
#define WROWS  16   // rows per write-kernel block (t row reused from registers)

// Order-preserving monotone map fp32 -> u32 (larger float => larger key).
__device__ __forceinline__ uint32_t fkey(float x) {
    uint32_t u = __float_as_uint(x);
    return (u & 0x80000000u) ? ~u : (u | 0x80000000u);
}
// Inverse of fkey (exact bit-level inverse).
__device__ __forceinline__ float inv_fkey(uint32_t k) {
    uint32_t u = (k & 0x80000000u) ? (k & 0x7FFFFFFFu) : ~k;
    return __uint_as_float(u);
}

// ---------------------------------------------------------------------------
// Fused selection kernel, one 1024-thread block per graph.
//   1. bitonic sort of t-keys, ONE ELEMENT PER THREAD in registers:
//      packed u64 = (key<<16)|idx. Steps with j<=32 use intra-wave
//      __shfl_xor (no barriers); j>=64 uses double-buffered LDS exchange
//      (1 barrier per step, 10 total vs R5's 55).
//   2. 33-iter binary search of key space for the K-th largest product key T.
//      Per-row searches restricted to tracked [rlo,rhi) intervals (R5-validated
//      monotone shrinking). Reduction: wave shuffle tree -> double-buffered
//      wsum -> ALL threads sum 16 partials (broadcast reads) -> uniform local
//      lo/hi update. ONE barrier per iteration.
//   3. cnt_gt(T) tracked incrementally as cntHi (count at current hi; exact
//      0 for initial hi=0xFFFFFFFF) -> R = K - cntHi, no extra pass.
//   4. collect ties (key == T, diag excluded) into LDS, dump to global.
// Product s_i*t_j is monotone in t_j for fixed s_i (IEEE multiply); sign of
// s_i picks suffix/prefix direction. All comparisons on exact product keys.
// ---------------------------------------------------------------------------
__global__ __launch_bounds__(NNODES)
void select_kernel(const float* __restrict__ s, const float* __restrict__ t,
                   uint32_t* __restrict__ Tout, uint32_t* __restrict__ Rout,
                   uint32_t* __restrict__ eqCntG, uint32_t* __restrict__ eqIdxG) {
    const int g = blockIdx.x, i = threadIdx.x;
    __shared__ uint64_t xbuf[2][NNODES];   // sort exchange buffers
    __shared__ float    tvs[NNODES];       // t values in key-ascending order
    __shared__ uint16_t sidx[NNODES];      // original index at sorted position
    __shared__ uint32_t wsum[2][16];       // double-buffered per-wave partials
    __shared__ uint32_t sEqCnt;
    __shared__ uint32_t sEqList[EQCAP];

    const float tv_i = t[g * NNODES + i];
    uint64_t e = ((uint64_t)fkey(tv_i) << 16) | (uint32_t)i;
    if (i == 0) sEqCnt = 0u;

    // ---- bitonic sort, element-per-thread ----
    int pb = 0;
    for (int k = 2; k <= NNODES; k <<= 1) {
        for (int j = k >> 1; j > 0; j >>= 1) {
            uint64_t pe;
            if (j >= 64) {                         // cross-wave: LDS exchange
                xbuf[pb][i] = e;
                __syncthreads();
                pe = xbuf[pb][i ^ j];
                pb ^= 1;                           // alternate buffers: 1 barrier/step
            } else {                               // intra-wave: shuffle
                pe = (uint64_t)__shfl_xor((unsigned long long)e, j, 64);
            }
            // position keeps min iff (lower of pair) XNOR (ascending region)
            bool keepSmall = (((i & j) == 0) == ((i & k) == 0));
            e = (keepSmall == (pe < e)) ? pe : e;  // pe==e impossible (idx distinct)
        }
    }
    tvs[i]  = inv_fkey((uint32_t)(e >> 16));
    sidx[i] = (uint16_t)(e & 0xFFFFu);

    const float sv = s[g * NNODES + i];
    const bool sneg = (__float_as_uint(sv) >> 31) != 0;
    const uint32_t kdiag = fkey(sv * tv_i);        // diagonal element (excluded)
    __syncthreads();

    // boundary search within [lo_,hi_): for s>=+0 rows, (key>cand) true on
    // suffix starting at b; for s<0 rows, prefix ending at b. b monotone in cand.
    auto srchRange = [&](uint32_t cand, int lo_, int hi_) -> int {
        while (lo_ < hi_) {
            int mid = (lo_ + hi_) >> 1;
            bool pred = fkey(sv * tvs[mid]) > cand;
            bool goLeft = sneg ? !pred : pred;
            if (goLeft) hi_ = mid; else lo_ = mid + 1;
        }
        return lo_;
    };

    // ---- binary search in key space: minimal T with cnt_gt(T) < K ----
    uint32_t lo = 0u, hi = 0xFFFFFFFFu;
    uint32_t cntHi = 0u;            // cnt_gt(hi): exact for hi=0xFFFFFFFF
    int rlo = 0, rhi = NNODES;      // per-row interval covering b(c) for c in [lo,hi]
    for (int it = 0; it < 33; ++it) {
        const uint32_t mid = lo + ((hi - lo) >> 1);
        const int b = srchRange(mid, rlo, rhi);
        uint32_t c = sneg ? (uint32_t)b : (uint32_t)(NNODES - b);
        if (kdiag > mid) c--;                      // exclude diagonal (c>=1 then)
        uint32_t r = c;
        for (int off = 32; off; off >>= 1) r += __shfl_down(r, off);
        if ((i & 63) == 0) wsum[pb][i >> 6] = r;
        __syncthreads();                           // ONE barrier per iteration
        uint32_t tot = 0;
        #pragma unroll
        for (int w = 0; w < 16; ++w) tot += wsum[pb][w];
        pb ^= 1;
        if (lo < hi) {                             // uniform update in every thread
            if (tot < TOPK) { hi = mid; cntHi = tot;
                              if (!sneg) rhi = b; else rlo = b; }
            else            { lo = mid + 1;
                              if (!sneg) rlo = b; else rhi = b; }
        }
    }
    const uint32_t T = lo;                         // lo==hi; cnt_gt(T)==cntHi
    if (i == 0) { Tout[g] = T; Rout[g] = TOPK - cntHi; }

    // ---- collect ties (key == T), diagonal excluded ----
    auto bound = [&](bool ge) -> int {
        int lo_ = 0, hi_ = NNODES;
        while (lo_ < hi_) {
            int mid = (lo_ + hi_) >> 1;
            uint32_t k = fkey(sv * tvs[mid]);
            bool pred = ge ? (k >= T) : (k > T);
            bool goLeft = sneg ? !pred : pred;
            if (goLeft) hi_ = mid; else lo_ = mid + 1;
        }
        return lo_;
    };
    int e0, e1;
    if (!sneg) { e0 = bound(true);  e1 = bound(false); }   // equals = [ge, gt)
    else       { e0 = bound(false); e1 = bound(true);  }   // equals = [gt, ge)
    for (int p = e0; p < e1; ++p) {
        uint32_t j = sidx[p];
        if ((int)j == i) continue;
        uint32_t slot = atomicAdd(&sEqCnt, 1u);
        if (slot < EQCAP) sEqList[slot] = (uint32_t)(i * NNODES) + j;
    }
    __syncthreads();
    uint32_t E = sEqCnt; if (E > EQCAP) E = EQCAP;
    if (i == 0) eqCntG[g] = E;
    for (uint32_t p = i; p < E; p += NNODES) eqIdxG[g * EQCAP + p] = sEqList[p];
}

// ---------------------------------------------------------------------------
// Output write: out = (key > T) && (i != j). One block per 16 rows of one
// graph; the t-row float4 stays in registers across rows (16x L2-read reuse).
// float4 stores, fully coalesced. ~512 MiB -> HBM-write-bound.
// ---------------------------------------------------------------------------
__global__ __launch_bounds__(256)
void write_kernel(const float* __restrict__ s, const float* __restrict__ t,
                  const uint32_t* __restrict__ Tin, float* __restrict__ out) {
    const int b  = blockIdx.x;                 // g*(N/WROWS) + rowblock
    const int g  = b >> 6;                     // / (NNODES/WROWS) == 64
    const int i0 = (b & 63) * WROWS;
    const uint32_t T = Tin[g];
    const float4 tv = ((const float4*)(t + (size_t)g * NNODES))[threadIdx.x];
    const int j0 = threadIdx.x * 4;
    float4* orow = (float4*)(out + (size_t)g * NNODES * NNODES + (size_t)i0 * NNODES);
    #pragma unroll
    for (int r = 0; r < WROWS; ++r) {
        const int i = i0 + r;
        const float sv = s[(size_t)g * NNODES + i];
        float4 o;
        o.x = (fkey(sv * tv.x) > T && (j0 + 0) != i) ? 1.0f : 0.0f;
        o.y = (fkey(sv * tv.y) > T && (j0 + 1) != i) ? 1.0f : 0.0f;
        o.z = (fkey(sv * tv.z) > T && (j0 + 2) != i) ? 1.0f : 0.0f;
        o.w = (fkey(sv * tv.w) > T && (j0 + 3) != i) ? 1.0f : 0.0f;
        orow[(size_t)r * (NNODES / 4) + threadIdx.x] = o;
    }
}

// ---------------------------------------------------------------------------
// Among ties, set the R smallest flat indices to 1 (matches jax.lax.top_k
// tie-breaking: lower flat index wins).
// ---------------------------------------------------------------------------
__global__ __launch_bounds__(256)
void scatter_kernel(const uint32_t* __restrict__ eqCnt, const uint32_t* __restrict__ eqIdx,
                    const uint32_t* __restrict__ Rin, float* __restrict__ out) {
    const int g = blockIdx.x;
    uint32_t E = eqCnt[g];
    const uint32_t R = Rin[g];
    __shared__ uint32_t se[EQCAP];
    for (uint32_t p = threadIdx.x; p < E; p += blockDim.x) se[p] = eqIdx[g * EQCAP + p];
    __syncthreads();
    for (uint32_t p = threadIdx.x; p < E; p += blockDim.x) {
        uint32_t v = se[p], rank = 0;
        for (uint32_t q = 0; q < E; ++q) rank += (se[q] < v) ? 1u : 0u;
        if (rank < R) out[(size_t)g * NNODES * NNODES + v] = 1.0f;
    }
}

extern "C" void kernel_launch(void* const* d_in, const int* in_sizes, int n_in,
                              void* d_out, int out_size, void* d_ws, size_t ws_size,
                              hipStream_t stream) {
    // inputs: x (unused), emb_s [G,N,1], emb_t [G,1,N] -- all float32
    const float* s = (const float*)d_in[1];
    const float* t = (const float*)d_in[2];
    float* out = (float*)d_out;

    char* ws = (char*)d_ws;
    uint32_t* Tbuf  = (uint32_t*)ws; ws += (size_t)NGRAPH * 4;
    uint32_t* Rbuf  = (uint32_t*)ws; ws += (size_t)NGRAPH * 4;
    uint32_t* eqCnt = (uint32_t*)ws; ws += (size_t)NGRAPH * 4;
    uint32_t* eqIdx = (uint32_t*)ws; ws += (size_t)NGRAPH * EQCAP * 4;

    select_kernel<<<NGRAPH, NNODES, 0, stream>>>(s, t, Tbuf, Rbuf, eqCnt, eqIdx);
    write_kernel<<<NGRAPH * (NNODES / WROWS), 256, 0, stream>>>(s, t, Tbuf, out);
    scatter_kernel<<<NGRAPH, 256, 0, stream>>>(eqCnt, eqIdx, Rbuf, out);
}

// Round 7
// 150.163 us; speedup vs baseline: 1.0105x; 1.0105x over previous
//
#include <hip/hip_runtime.h>
#include <stdint.h>

#define NNODES 1024
#define NGRAPH 128
#define TOPK   16384
#define EQCAP  4096

// Order-preserving monotone map fp32 -> u32 (larger float => larger key).
__device__ __forceinline__ uint32_t fkey(float x) {
    uint32_t u = __float_as_uint(x);
    return (u & 0x80000000u) ? ~u : (u | 0x80000000u);
}

// ---------------------------------------------------------------------------
// Fused selection kernel, one 1024-thread block per graph.
//   1. bitonic-sort t by key (R5-validated LDS sort).
//   2. 4-ary search (18 iters) of the 32-bit key space for the K-th largest
//      product key T. 3 candidates per iteration; per-row boundary searches
//      restricted by the tracked [rlo,rhi) interval AND chained off the
//      previous candidate's boundary (boundary is monotone in the candidate).
//      The 3 counts (<=2^20 each) pack into one u64: one u64 wave shuffle
//      reduce + one u64 LDS atomicAdd per wave into a TRIPLE-BUFFERED total,
//      ONE barrier per iteration, uniform update in every thread.
//      (R4/R6 lesson: the block is DS-pipe bound and barriers overlap across
//      16 waves -- minimize DS lane-ops and serial latency rounds, not
//      barrier count alone.)
//   3. cnt_gt(hi) tracked incrementally (cntHi) -> R = K - cntHi, no extra
//      pass (exact: init hi=0xFFFFFFFF has cnt 0).
//   4. collect ties (key == T, diag excluded) into LDS, dump to global.
// Product s_i*t_j is monotone in t_j for fixed s_i (IEEE multiply); sign of
// s_i picks suffix/prefix direction. All comparisons on exact product keys.
// ---------------------------------------------------------------------------
__global__ __launch_bounds__(NNODES)
void select_kernel(const float* __restrict__ s, const float* __restrict__ t,
                   uint32_t* __restrict__ Tout, uint32_t* __restrict__ Rout,
                   uint32_t* __restrict__ eqCntG, uint32_t* __restrict__ eqIdxG) {
    const int g = blockIdx.x, i = threadIdx.x;
    __shared__ float    torig[NNODES];
    __shared__ uint32_t skey[NNODES];
    __shared__ uint16_t sidx[NNODES];
    __shared__ float    tvs[NNODES];     // t values in key-ascending order
    __shared__ uint64_t sTot[3];         // triple-buffered packed totals
    __shared__ uint32_t sEqCnt;
    __shared__ uint32_t sEqList[EQCAP];

    const float tv_i = t[g * NNODES + i];
    torig[i] = tv_i;
    skey[i]  = fkey(tv_i);
    sidx[i]  = (uint16_t)i;
    if (i == 0) sEqCnt = 0u;
    if (i < 3)  sTot[i] = 0ull;

    // ---- bitonic sort (keys + payload indices) -- R5 verbatim ----
    for (int k = 2; k <= NNODES; k <<= 1) {
        for (int j = k >> 1; j > 0; j >>= 1) {
            __syncthreads();
            int partner = i ^ j;
            if (partner > i) {
                bool asc = ((i & k) == 0);
                uint32_t a = skey[i], b = skey[partner];
                if ((a > b) == asc) {
                    skey[i] = b; skey[partner] = a;
                    uint16_t ia = sidx[i]; sidx[i] = sidx[partner]; sidx[partner] = ia;
                }
            }
        }
    }
    __syncthreads();
    tvs[i] = torig[sidx[i]];

    const float sv = s[g * NNODES + i];
    const bool sneg = (__float_as_uint(sv) >> 31) != 0;
    const uint32_t kdiag = fkey(sv * tv_i);   // diagonal element (excluded)
    __syncthreads();

    // boundary search within [lo_,hi_): for s>=+0 rows, (key>cand) true on
    // suffix starting at b; for s<0 rows, prefix ending at b. b monotone in
    // cand (non-decreasing for pos rows, non-increasing for neg rows).
    auto srchRange = [&](uint32_t cand, int lo_, int hi_) -> int {
        while (lo_ < hi_) {
            int mid = (lo_ + hi_) >> 1;
            bool pred = fkey(sv * tvs[mid]) > cand;
            bool goLeft = sneg ? !pred : pred;
            if (goLeft) hi_ = mid; else lo_ = mid + 1;
        }
        return lo_;
    };

    // ---- 4-ary search in key space: minimal T with cnt_gt(T) < K ----
    // Range shrinks r -> ~r/4+1 per iter; 2^32 closes in <=17 iters, run 18.
    uint32_t lo = 0u, hi = 0xFFFFFFFFu;
    uint32_t cntHi = 0u;            // cnt_gt(hi): exact for hi=0xFFFFFFFF
    int rlo = 0, rhi = NNODES;      // per-row interval covering b(c), c in [lo,hi]
    for (int it = 0; it < 18; ++it) {
        const uint32_t range = hi - lo;
        const uint32_t c0 = lo + (uint32_t)(((uint64_t)range * 1) >> 2);
        const uint32_t c1 = lo + (uint32_t)(((uint64_t)range * 2) >> 2);
        const uint32_t c2 = lo + (uint32_t)(((uint64_t)range * 3) >> 2);
        int b0, b1, b2;
        if (!sneg) {   // boundaries non-decreasing in cand: chain lower bounds
            b0 = srchRange(c0, rlo, rhi);
            b1 = srchRange(c1, b0,  rhi);
            b2 = srchRange(c2, b1,  rhi);
        } else {       // non-increasing: chain upper bounds
            b0 = srchRange(c0, rlo, rhi);
            b1 = srchRange(c1, rlo, b0);
            b2 = srchRange(c2, rlo, b1);
        }
        uint32_t n0 = sneg ? (uint32_t)b0 : (uint32_t)(NNODES - b0);
        uint32_t n1 = sneg ? (uint32_t)b1 : (uint32_t)(NNODES - b1);
        uint32_t n2 = sneg ? (uint32_t)b2 : (uint32_t)(NNODES - b2);
        if (kdiag > c0) n0--;                 // exclude diagonal
        if (kdiag > c1) n1--;
        if (kdiag > c2) n2--;
        // pack 3 counts (<=2^20 after 1024-row sum) into 21-bit fields
        uint64_t r = (uint64_t)n0 | ((uint64_t)n1 << 21) | ((uint64_t)n2 << 42);
        for (int off = 32; off; off >>= 1)
            r += (uint64_t)__shfl_down((unsigned long long)r, off);
        if ((i & 63) == 0)
            atomicAdd((unsigned long long*)&sTot[it % 3], (unsigned long long)r);
        if (i == 0) sTot[(it + 1) % 3] = 0ull;   // zero next iter's buffer;
        // last read of that buffer was at iter it-2, separated by barrier(it-1)
        __syncthreads();                          // ONE barrier per iteration
        const uint64_t tot = sTot[it % 3];
        const uint32_t t0 = (uint32_t)(tot & 0x1FFFFFu);
        const uint32_t t1 = (uint32_t)((tot >> 21) & 0x1FFFFFu);
        const uint32_t t2 = (uint32_t)((tot >> 42) & 0x1FFFFFu);
        if (lo < hi) {                            // uniform update, every thread
            if (t0 < TOPK)      { hi = c0; cntHi = t0;
                                  if (!sneg) rhi = b0; else rlo = b0; }
            else if (t1 < TOPK) { lo = c0 + 1; hi = c1; cntHi = t1;
                                  if (!sneg) { rlo = b0; rhi = b1; }
                                  else       { rlo = b1; rhi = b0; } }
            else if (t2 < TOPK) { lo = c1 + 1; hi = c2; cntHi = t2;
                                  if (!sneg) { rlo = b1; rhi = b2; }
                                  else       { rlo = b2; rhi = b1; } }
            else                { lo = c2 + 1;
                                  if (!sneg) rlo = b2; else rhi = b2; }
        }
    }
    const uint32_t T = lo;                        // lo==hi; cnt_gt(T)==cntHi
    if (i == 0) { Tout[g] = T; Rout[g] = TOPK - cntHi; }

    // ---- collect ties (key == T), diagonal excluded -- R5 verbatim ----
    auto bound = [&](bool ge) -> int {
        int lo_ = 0, hi_ = NNODES;
        while (lo_ < hi_) {
            int mid = (lo_ + hi_) >> 1;
            uint32_t k = fkey(sv * tvs[mid]);
            bool pred = ge ? (k >= T) : (k > T);
            bool goLeft = sneg ? !pred : pred;
            if (goLeft) hi_ = mid; else lo_ = mid + 1;
        }
        return lo_;
    };
    int e0, e1;
    if (!sneg) { e0 = bound(true);  e1 = bound(false); }   // equals = [ge, gt)
    else       { e0 = bound(false); e1 = bound(true);  }   // equals = [gt, ge)
    for (int p = e0; p < e1; ++p) {
        uint32_t j = sidx[p];
        if ((int)j == i) continue;
        uint32_t slot = atomicAdd(&sEqCnt, 1u);
        if (slot < EQCAP) sEqList[slot] = (uint32_t)(i * NNODES) + j;
    }
    __syncthreads();
    uint32_t E = sEqCnt; if (E > EQCAP) E = EQCAP;
    if (i == 0) eqCntG[g] = E;
    for (uint32_t p = i; p < E; p += NNODES) eqIdxG[g * EQCAP + p] = sEqList[p];
}

// ---------------------------------------------------------------------------
// Output write: out = (key > T) && (i != j). One block per output row
// (R5-validated config); float4 stores. ~512 MiB -> HBM-write-bound.
// ---------------------------------------------------------------------------
__global__ __launch_bounds__(256)
void write_kernel(const float* __restrict__ s, const float* __restrict__ t,
                  const uint32_t* __restrict__ Tin, float* __restrict__ out) {
    const int b = blockIdx.x;           // g*1024 + i
    const int g = b >> 10, i = b & 1023;
    const uint32_t T = Tin[g];
    const float sv = s[(size_t)g * NNODES + i];
    const float4 tv = ((const float4*)(t + (size_t)g * NNODES))[threadIdx.x];
    const int j0 = threadIdx.x * 4;
    float4 r;
    r.x = (fkey(sv * tv.x) > T && (j0 + 0) != i) ? 1.0f : 0.0f;
    r.y = (fkey(sv * tv.y) > T && (j0 + 1) != i) ? 1.0f : 0.0f;
    r.z = (fkey(sv * tv.z) > T && (j0 + 2) != i) ? 1.0f : 0.0f;
    r.w = (fkey(sv * tv.w) > T && (j0 + 3) != i) ? 1.0f : 0.0f;
    ((float4*)(out + (size_t)g * NNODES * NNODES + (size_t)i * NNODES))[threadIdx.x] = r;
}

// ---------------------------------------------------------------------------
// Among ties, set the R smallest flat indices to 1 (matches jax.lax.top_k
// tie-breaking: lower flat index wins).
// ---------------------------------------------------------------------------
__global__ __launch_bounds__(256)
void scatter_kernel(const uint32_t* __restrict__ eqCnt, const uint32_t* __restrict__ eqIdx,
                    const uint32_t* __restrict__ Rin, float* __restrict__ out) {
    const int g = blockIdx.x;
    uint32_t E = eqCnt[g];
    const uint32_t R = Rin[g];
    __shared__ uint32_t se[EQCAP];
    for (uint32_t p = threadIdx.x; p < E; p += blockDim.x) se[p] = eqIdx[g * EQCAP + p];
    __syncthreads();
    for (uint32_t p = threadIdx.x; p < E; p += blockDim.x) {
        uint32_t v = se[p], rank = 0;
        for (uint32_t q = 0; q < E; ++q) rank += (se[q] < v) ? 1u : 0u;
        if (rank < R) out[(size_t)g * NNODES * NNODES + v] = 1.0f;
    }
}

extern "C" void kernel_launch(void* const* d_in, const int* in_sizes, int n_in,
                              void* d_out, int out_size, void* d_ws, size_t ws_size,
                              hipStream_t stream) {
    // inputs: x (unused), emb_s [G,N,1], emb_t [G,1,N] -- all float32
    const float* s = (const float*)d_in[1];
    const float* t = (const float*)d_in[2];
    float* out = (float*)d_out;

    char* ws = (char*)d_ws;
    uint32_t* Tbuf  = (uint32_t*)ws; ws += (size_t)NGRAPH * 4;
    uint32_t* Rbuf  = (uint32_t*)ws; ws += (size_t)NGRAPH * 4;
    uint32_t* eqCnt = (uint32_t*)ws; ws += (size_t)NGRAPH * 4;
    uint32_t* eqIdx = (uint32_t*)ws; ws += (size_t)NGRAPH * EQCAP * 4;

    select_kernel<<<NGRAPH, NNODES, 0, stream>>>(s, t, Tbuf, Rbuf, eqCnt, eqIdx);
    write_kernel<<<NGRAPH * NNODES, 256, 0, stream>>>(s, t, Tbuf, out);
    scatter_kernel<<<NGRAPH, 256, 0, stream>>>(eqCnt, eqIdx, Rbuf, out);
}

// Round 9
// 148.175 us; speedup vs baseline: 1.0240x; 1.0134x over previous
//
#include <hip/hip_runtime.h>
#include <stdint.h>

#define NNODES 1024
#define NGRAPH 128
#define TOPK   16384
#define EQCAP  4096
#define WROWS  8    // rows per write-kernel block

typedef float vfloat4 __attribute__((ext_vector_type(4)));  // native clang vec

// Order-preserving monotone map fp32 -> u32 (larger float => larger key).
__device__ __forceinline__ uint32_t fkey(float x) {
    uint32_t u = __float_as_uint(x);
    return (u & 0x80000000u) ? ~u : (u | 0x80000000u);
}
// Exact bit-level inverse of fkey.
__device__ __forceinline__ float inv_fkey(uint32_t k) {
    uint32_t u = (k & 0x80000000u) ? (k & 0x7FFFFFFFu) : ~k;
    return __uint_as_float(u);
}

// ---------------------------------------------------------------------------
// Fused selection kernel, one 1024-thread block per graph.
//   1. bitonic sort of t-keys, one element/thread in registers (R6-validated):
//      packed u64 = (key<<16)|idx; j<=32 steps via __shfl_xor (no barriers),
//      j>=64 via double-buffered LDS exchange -- 10 barriers vs 55.
//   2. 33-iter binary search of key space for the K-th largest product key T
//      (R5-verbatim loop: per-row searches restricted to tracked [rlo,rhi)
//      intervals; wave shuffle reduce -> wsum -> thread-0 sum -> LDS
//      broadcast). Thread 0 additionally tracks cntHi = cnt_gt(hi)
//      (R6/R7-validated) so no final exact-count pass is needed.
//   3. collect ties (key == T, diag excluded) into LDS, dump to global.
// Product s_i*t_j is monotone in t_j for fixed s_i (IEEE multiply); sign of
// s_i picks suffix/prefix direction. All comparisons on exact product keys.
// (R4/R6/R7 lesson: block is DS-pipe bound; minimize DS lane-ops. R5's
// search loop is the proven local optimum -- kept bit-identical.)
// ---------------------------------------------------------------------------
__global__ __launch_bounds__(NNODES)
void select_kernel(const float* __restrict__ s, const float* __restrict__ t,
                   uint32_t* __restrict__ Tout, uint32_t* __restrict__ Rout,
                   uint32_t* __restrict__ eqCntG, uint32_t* __restrict__ eqIdxG) {
    const int g = blockIdx.x, i = threadIdx.x;
    __shared__ uint64_t xbuf[2][NNODES];   // sort exchange buffers (16 KB)
    __shared__ float    tvs[NNODES];       // t values in key-ascending order
    __shared__ uint16_t sidx[NNODES];      // original index at sorted position
    __shared__ uint32_t wsum[16];
    __shared__ uint32_t sLo, sHi, sDir, sEqCnt;
    __shared__ uint32_t sEqList[EQCAP];

    const float tv_i = t[g * NNODES + i];
    uint64_t e = ((uint64_t)fkey(tv_i) << 16) | (uint32_t)i;
    if (i == 0) { sLo = 0u; sHi = 0xFFFFFFFFu; sEqCnt = 0u; }

    // ---- bitonic sort, element-per-thread (R6-validated) ----
    int pb = 0;
    for (int k = 2; k <= NNODES; k <<= 1) {
        for (int j = k >> 1; j > 0; j >>= 1) {
            uint64_t pe;
            if (j >= 64) {                         // cross-wave: LDS exchange
                xbuf[pb][i] = e;
                __syncthreads();
                pe = xbuf[pb][i ^ j];
                pb ^= 1;                           // dbuf: 1 barrier per step
            } else {                               // intra-wave: shuffle
                pe = (uint64_t)__shfl_xor((unsigned long long)e, j, 64);
            }
            bool keepSmall = (((i & j) == 0) == ((i & k) == 0));
            e = (keepSmall == (pe < e)) ? pe : e;  // pe==e impossible (idx distinct)
        }
    }
    tvs[i]  = inv_fkey((uint32_t)(e >> 16));
    sidx[i] = (uint16_t)(e & 0xFFFFu);

    const float sv = s[g * NNODES + i];
    const bool sneg = (__float_as_uint(sv) >> 31) != 0;
    const uint32_t kdiag = fkey(sv * tv_i);   // diagonal element (excluded)
    __syncthreads();

    // boundary search within [lo_,hi_): for s>=+0 rows, (key>cand) true on
    // suffix starting at b; for s<0 rows, prefix ending at b. b monotone in cand.
    auto srchRange = [&](uint32_t cand, int lo_, int hi_) -> int {
        while (lo_ < hi_) {
            int mid = (lo_ + hi_) >> 1;
            bool pred = fkey(sv * tvs[mid]) > cand;
            bool goLeft = sneg ? !pred : pred;
            if (goLeft) hi_ = mid; else lo_ = mid + 1;
        }
        return lo_;
    };

    int rlo = 0, rhi = NNODES;       // per-row interval covering b(c), c in [sLo,sHi]
    uint32_t cntHi = 0u;             // thread 0 only: cnt_gt(sHi), exact at init

    // ---- binary search in key space: minimal T with cnt_gt(T) < K (R5 loop) ----
    for (int it = 0; it < 33; ++it) {
        const uint32_t lo = sLo, hi = sHi;       // uniform (read after barrier)
        const uint32_t mid = lo + ((hi - lo) >> 1);
        const int b = srchRange(mid, rlo, rhi);
        uint32_t c = sneg ? (uint32_t)b : (uint32_t)(NNODES - b);
        if (kdiag > mid) c--;                    // exclude diagonal if it qualified
        uint32_t r = c;
        for (int off = 32; off; off >>= 1) r += __shfl_down(r, off);
        if ((i & 63) == 0) wsum[i >> 6] = r;
        __syncthreads();
        if (i == 0 && lo < hi) {
            uint32_t tot = 0;
            for (int w = 0; w < 16; ++w) tot += wsum[w];
            if (tot < TOPK) { sHi = mid; sDir = 0u; cntHi = tot; }  // go left
            else            { sLo = mid + 1; sDir = 1u; }           // go right
        }
        __syncthreads();
        if (lo < hi) {
            // shrink per-row interval (monotonicity of b in cand)
            if (sDir == 0u) { if (!sneg) rhi = b; else rlo = b; }
            else            { if (!sneg) rlo = b; else rhi = b; }
        }
    }
    const uint32_t T = sLo;                      // sLo==sHi; cnt_gt(T)==cntHi
    if (i == 0) { Tout[g] = T; Rout[g] = TOPK - cntHi; }

    // ---- collect ties (key == T), diagonal excluded (R5 verbatim) ----
    auto bound = [&](bool ge) -> int {
        int lo_ = 0, hi_ = NNODES;
        while (lo_ < hi_) {
            int mid = (lo_ + hi_) >> 1;
            uint32_t k = fkey(sv * tvs[mid]);
            bool pred = ge ? (k >= T) : (k > T);
            bool goLeft = sneg ? !pred : pred;
            if (goLeft) hi_ = mid; else lo_ = mid + 1;
        }
        return lo_;
    };
    int e0, e1;
    if (!sneg) { e0 = bound(true);  e1 = bound(false); }   // equals = [ge, gt)
    else       { e0 = bound(false); e1 = bound(true);  }   // equals = [gt, ge)
    for (int p = e0; p < e1; ++p) {
        uint32_t j = sidx[p];
        if ((int)j == i) continue;
        uint32_t slot = atomicAdd(&sEqCnt, 1u);
        if (slot < EQCAP) sEqList[slot] = (uint32_t)(i * NNODES) + j;
    }
    __syncthreads();
    uint32_t E = sEqCnt; if (E > EQCAP) E = EQCAP;
    if (i == 0) eqCntG[g] = E;
    for (uint32_t p = i; p < E; p += NNODES) eqIdxG[g * EQCAP + p] = sEqList[p];
}

// ---------------------------------------------------------------------------
// Output write: out = (key > T) && (i != j). One block per 8 rows; the t-row
// float4 stays in registers across rows (8x fewer waves than 1-row/block,
// amortizing per-wave overhead); s is a wave-uniform scalar load per row.
// Non-temporal native-vec4 stores. ~512 MiB -> HBM-write-bound.
// ---------------------------------------------------------------------------
__global__ __launch_bounds__(256)
void write_kernel(const float* __restrict__ s, const float* __restrict__ t,
                  const uint32_t* __restrict__ Tin, float* __restrict__ out) {
    const int b  = blockIdx.x;                 // g*(NNODES/WROWS) + rowblock
    const int g  = b >> 7;                     // NNODES/WROWS == 128
    const int i0 = (b & 127) * WROWS;
    const uint32_t T = Tin[g];
    const vfloat4 tv = ((const vfloat4*)(t + (size_t)g * NNODES))[threadIdx.x];
    const int j0 = threadIdx.x * 4;
    vfloat4* obase = (vfloat4*)(out + (size_t)g * NNODES * NNODES + (size_t)i0 * NNODES);
    #pragma unroll
    for (int r = 0; r < WROWS; ++r) {
        const int i = i0 + r;
        const float sv = s[(size_t)g * NNODES + i];
        vfloat4 o;
        o.x = (fkey(sv * tv.x) > T && (j0 + 0) != i) ? 1.0f : 0.0f;
        o.y = (fkey(sv * tv.y) > T && (j0 + 1) != i) ? 1.0f : 0.0f;
        o.z = (fkey(sv * tv.z) > T && (j0 + 2) != i) ? 1.0f : 0.0f;
        o.w = (fkey(sv * tv.w) > T && (j0 + 3) != i) ? 1.0f : 0.0f;
        __builtin_nontemporal_store(o, &obase[(size_t)r * (NNODES / 4) + threadIdx.x]);
    }
}

// ---------------------------------------------------------------------------
// Among ties, set the R smallest flat indices to 1 (matches jax.lax.top_k
// tie-breaking: lower flat index wins).
// ---------------------------------------------------------------------------
__global__ __launch_bounds__(256)
void scatter_kernel(const uint32_t* __restrict__ eqCnt, const uint32_t* __restrict__ eqIdx,
                    const uint32_t* __restrict__ Rin, float* __restrict__ out) {
    const int g = blockIdx.x;
    uint32_t E = eqCnt[g];
    const uint32_t R = Rin[g];
    __shared__ uint32_t se[EQCAP];
    for (uint32_t p = threadIdx.x; p < E; p += blockDim.x) se[p] = eqIdx[g * EQCAP + p];
    __syncthreads();
    for (uint32_t p = threadIdx.x; p < E; p += blockDim.x) {
        uint32_t v = se[p], rank = 0;
        for (uint32_t q = 0; q < E; ++q) rank += (se[q] < v) ? 1u : 0u;
        if (rank < R) out[(size_t)g * NNODES * NNODES + v] = 1.0f;
    }
}

extern "C" void kernel_launch(void* const* d_in, const int* in_sizes, int n_in,
                              void* d_out, int out_size, void* d_ws, size_t ws_size,
                              hipStream_t stream) {
    // inputs: x (unused), emb_s [G,N,1], emb_t [G,1,N] -- all float32
    const float* s = (const float*)d_in[1];
    const float* t = (const float*)d_in[2];
    float* out = (float*)d_out;

    char* ws = (char*)d_ws;
    uint32_t* Tbuf  = (uint32_t*)ws; ws += (size_t)NGRAPH * 4;
    uint32_t* Rbuf  = (uint32_t*)ws; ws += (size_t)NGRAPH * 4;
    uint32_t* eqCnt = (uint32_t*)ws; ws += (size_t)NGRAPH * 4;
    uint32_t* eqIdx = (uint32_t*)ws; ws += (size_t)NGRAPH * EQCAP * 4;

    select_kernel<<<NGRAPH, NNODES, 0, stream>>>(s, t, Tbuf, Rbuf, eqCnt, eqIdx);
    write_kernel<<<NGRAPH * (NNODES / WROWS), 256, 0, stream>>>(s, t, Tbuf, out);
    scatter_kernel<<<NGRAPH, 256, 0, stream>>>(eqCnt, eqIdx, Rbuf, out);
}